// Round 2
// baseline (6842.800 us; speedup 1.0000x reference)
//
#include <hip/hip_runtime.h>
#include <hip/hip_bf16.h>

#define NN 50000
#define NE 200000
#define HD 128

using bf16 = __hip_bfloat16;

// Tile geometry everywhere: 256 threads, 64 rows x 128 cols.
// tx = tid&15 (owns cols tx*8..tx*8+7), ty = tid>>4 (owns rows ty*4..ty*4+3).

// ---------------------------------------------------------------------------
// zero fp32 buffer (float4)
// ---------------------------------------------------------------------------
__global__ __launch_bounds__(256) void zero_k(float4* __restrict__ p, long n4) {
    long i = (long)blockIdx.x * blockDim.x + threadIdx.x;
    if (i < n4) p[i] = float4{0.f, 0.f, 0.f, 0.f};
}

__global__ __launch_bounds__(256) void zero_out_k(float* __restrict__ p, long n) {
    long i = (long)blockIdx.x * blockDim.x + threadIdx.x;
    if (i < n) p[i] = 0.f;
}

// ---------------------------------------------------------------------------
// Fused 2-layer encoder: out = relu(A[M,KIN] @ W1 + b1) @ W2 + b2   [M,128]
// ---------------------------------------------------------------------------
template<int KIN, typename OutT>
__global__ __launch_bounds__(256) void enc_fused_k(
    const float* __restrict__ A,
    const float* __restrict__ W1, const float* __restrict__ b1,
    const float* __restrict__ W2, const float* __restrict__ b2,
    OutT* __restrict__ out, int M)
{
    __shared__ float As[64][33];
    __shared__ float Ws[32][HD];
    __shared__ float P[64][HD + 1];
    const int tid = threadIdx.x, tx = tid & 15, ty = tid >> 4;
    const int bm = blockIdx.x * 64;
    float acc[4][8] = {};

    // Phase A: hidden = A @ W1 (KIN <= 32, single padded chunk)
    {
        int r = tid >> 2, c0 = (tid & 3) * 8, gr = bm + r;
#pragma unroll
        for (int i = 0; i < 8; ++i) {
            int c = c0 + i;
            As[r][c] = (gr < M && c < KIN) ? A[(long)gr * KIN + c] : 0.f;
        }
        int k = tid >> 3, n0 = (tid & 7) * 16;
#pragma unroll
        for (int i = 0; i < 16; ++i)
            Ws[k][n0 + i] = (k < KIN) ? W1[k * HD + n0 + i] : 0.f;
        __syncthreads();
#pragma unroll
        for (int k2 = 0; k2 < 32; ++k2) {
            float a0 = As[ty * 4 + 0][k2], a1 = As[ty * 4 + 1][k2];
            float a2 = As[ty * 4 + 2][k2], a3 = As[ty * 4 + 3][k2];
#pragma unroll
            for (int j = 0; j < 8; ++j) {
                float w = Ws[k2][tx * 8 + j];
                acc[0][j] = fmaf(a0, w, acc[0][j]);
                acc[1][j] = fmaf(a1, w, acc[1][j]);
                acc[2][j] = fmaf(a2, w, acc[2][j]);
                acc[3][j] = fmaf(a3, w, acc[3][j]);
            }
        }
        __syncthreads();
    }
    // hidden -> P (relu + b1)
#pragma unroll
    for (int i = 0; i < 4; ++i) {
        int row = ty * 4 + i;
#pragma unroll
        for (int j = 0; j < 8; ++j) {
            int col = tx * 8 + j;
            P[row][col] = fmaxf(acc[i][j] + b1[col], 0.f);
            acc[i][j] = 0.f;
        }
    }
    __syncthreads();
    // Phase B: out = P @ W2 + b2
    for (int kk = 0; kk < HD; kk += 32) {
        int k = tid >> 3, n0 = (tid & 7) * 16;
#pragma unroll
        for (int i = 0; i < 16; ++i)
            Ws[k][n0 + i] = W2[(kk + k) * HD + n0 + i];
        __syncthreads();
#pragma unroll
        for (int k2 = 0; k2 < 32; ++k2) {
            float a0 = P[ty * 4 + 0][kk + k2], a1 = P[ty * 4 + 1][kk + k2];
            float a2 = P[ty * 4 + 2][kk + k2], a3 = P[ty * 4 + 3][kk + k2];
#pragma unroll
            for (int j = 0; j < 8; ++j) {
                float w = Ws[k2][tx * 8 + j];
                acc[0][j] = fmaf(a0, w, acc[0][j]);
                acc[1][j] = fmaf(a1, w, acc[1][j]);
                acc[2][j] = fmaf(a2, w, acc[2][j]);
                acc[3][j] = fmaf(a3, w, acc[3][j]);
            }
        }
        __syncthreads();
    }
#pragma unroll
    for (int i = 0; i < 4; ++i) {
        int gr = bm + ty * 4 + i;
        if (gr >= M) continue;
#pragma unroll
        for (int j = 0; j < 8; ++j) {
            int col = tx * 8 + j;
            out[(long)gr * HD + col] = OutT(acc[i][j] + b2[col]);
        }
    }
}

// ---------------------------------------------------------------------------
// Dual GEMM: Hs = h @ W1a, Hd = h @ W1b  (shared A tile)
// ---------------------------------------------------------------------------
__global__ __launch_bounds__(256) void dualgemm_k(
    const float* __restrict__ h,
    const float* __restrict__ W1a, const float* __restrict__ W1b,
    float* __restrict__ Hs, float* __restrict__ Hd, int M)
{
    __shared__ float As[64][33];
    __shared__ float Wa[32][HD];
    __shared__ float Wb[32][HD];
    const int tid = threadIdx.x, tx = tid & 15, ty = tid >> 4;
    const int bm = blockIdx.x * 64;
    float acc1[4][8] = {}, acc2[4][8] = {};

    for (int kk = 0; kk < HD; kk += 32) {
        int r = tid >> 2, c0 = (tid & 3) * 8, gr = bm + r;
#pragma unroll
        for (int i = 0; i < 8; ++i) {
            int c = c0 + i;
            As[r][c] = (gr < M) ? h[(long)gr * HD + kk + c] : 0.f;
        }
        int k = tid >> 3, n0 = (tid & 7) * 16;
#pragma unroll
        for (int i = 0; i < 16; ++i) {
            Wa[k][n0 + i] = W1a[(kk + k) * HD + n0 + i];
            Wb[k][n0 + i] = W1b[(kk + k) * HD + n0 + i];
        }
        __syncthreads();
#pragma unroll
        for (int k2 = 0; k2 < 32; ++k2) {
            float a0 = As[ty * 4 + 0][k2], a1 = As[ty * 4 + 1][k2];
            float a2 = As[ty * 4 + 2][k2], a3 = As[ty * 4 + 3][k2];
#pragma unroll
            for (int j = 0; j < 8; ++j) {
                float wa = Wa[k2][tx * 8 + j];
                acc1[0][j] = fmaf(a0, wa, acc1[0][j]);
                acc1[1][j] = fmaf(a1, wa, acc1[1][j]);
                acc1[2][j] = fmaf(a2, wa, acc1[2][j]);
                acc1[3][j] = fmaf(a3, wa, acc1[3][j]);
                float wb = Wb[k2][tx * 8 + j];
                acc2[0][j] = fmaf(a0, wb, acc2[0][j]);
                acc2[1][j] = fmaf(a1, wb, acc2[1][j]);
                acc2[2][j] = fmaf(a2, wb, acc2[2][j]);
                acc2[3][j] = fmaf(a3, wb, acc2[3][j]);
            }
        }
        __syncthreads();
    }
#pragma unroll
    for (int i = 0; i < 4; ++i) {
        int gr = bm + ty * 4 + i;
        if (gr >= M) continue;
#pragma unroll
        for (int j = 0; j < 8; ++j) {
            int col = tx * 8 + j;
            Hs[(long)gr * HD + col] = acc1[i][j];
            Hd[(long)gr * HD + col] = acc2[i][j];
        }
    }
}

// ---------------------------------------------------------------------------
// Fused edge message kernel:
//   P = relu(e@W1c + b1 + Hs[src] + Hd[dst]);  m = P@W2 + b2;  agg[dst] += m
// ---------------------------------------------------------------------------
__global__ __launch_bounds__(256) void edge_msg_k(
    const bf16* __restrict__ e,
    const float* __restrict__ Hs, const float* __restrict__ Hd,
    const int* __restrict__ src, const int* __restrict__ dst,
    const float* __restrict__ W1c, const float* __restrict__ b1,
    const float* __restrict__ W2, const float* __restrict__ b2,
    float* __restrict__ agg, int E)
{
    __shared__ float As[64][33];
    __shared__ float Ws[32][HD];
    __shared__ float P[64][HD + 1];
    const int tid = threadIdx.x, tx = tid & 15, ty = tid >> 4;
    const int bm = blockIdx.x * 64;
    float acc[4][8] = {};

    // Phase A: Ec = e @ W1c
    for (int kk = 0; kk < HD; kk += 32) {
        int r = tid >> 2, c0 = (tid & 3) * 8, gr = bm + r;
        const bf16* ep = e + (long)gr * HD + kk + c0;
#pragma unroll
        for (int i = 0; i < 8; ++i)
            As[r][c0 + i] = (gr < E) ? __bfloat162float(ep[i]) : 0.f;
        int k = tid >> 3, n0 = (tid & 7) * 16;
#pragma unroll
        for (int i = 0; i < 16; ++i)
            Ws[k][n0 + i] = W1c[(kk + k) * HD + n0 + i];
        __syncthreads();
#pragma unroll
        for (int k2 = 0; k2 < 32; ++k2) {
            float a0 = As[ty * 4 + 0][k2], a1 = As[ty * 4 + 1][k2];
            float a2 = As[ty * 4 + 2][k2], a3 = As[ty * 4 + 3][k2];
#pragma unroll
            for (int j = 0; j < 8; ++j) {
                float w = Ws[k2][tx * 8 + j];
                acc[0][j] = fmaf(a0, w, acc[0][j]);
                acc[1][j] = fmaf(a1, w, acc[1][j]);
                acc[2][j] = fmaf(a2, w, acc[2][j]);
                acc[3][j] = fmaf(a3, w, acc[3][j]);
            }
        }
        __syncthreads();
    }
    // gathers + bias + relu -> P
#pragma unroll
    for (int i = 0; i < 4; ++i) {
        int row = ty * 4 + i, edge = bm + row;
        if (edge < E) {
            int s = src[edge], d = dst[edge];
            const float4* hs4 = reinterpret_cast<const float4*>(Hs + (long)s * HD + tx * 8);
            const float4* hd4 = reinterpret_cast<const float4*>(Hd + (long)d * HD + tx * 8);
            float4 sa = hs4[0], sb = hs4[1], da = hd4[0], db = hd4[1];
            float g[8] = {sa.x + da.x, sa.y + da.y, sa.z + da.z, sa.w + da.w,
                          sb.x + db.x, sb.y + db.y, sb.z + db.z, sb.w + db.w};
#pragma unroll
            for (int j = 0; j < 8; ++j) {
                int col = tx * 8 + j;
                P[row][col] = fmaxf(acc[i][j] + b1[col] + g[j], 0.f);
                acc[i][j] = 0.f;
            }
        } else {
#pragma unroll
            for (int j = 0; j < 8; ++j) { P[row][tx * 8 + j] = 0.f; acc[i][j] = 0.f; }
        }
    }
    __syncthreads();
    // Phase B: m = P @ W2
    for (int kk = 0; kk < HD; kk += 32) {
        int k = tid >> 3, n0 = (tid & 7) * 16;
#pragma unroll
        for (int i = 0; i < 16; ++i)
            Ws[k][n0 + i] = W2[(kk + k) * HD + n0 + i];
        __syncthreads();
#pragma unroll
        for (int k2 = 0; k2 < 32; ++k2) {
            float a0 = P[ty * 4 + 0][kk + k2], a1 = P[ty * 4 + 1][kk + k2];
            float a2 = P[ty * 4 + 2][kk + k2], a3 = P[ty * 4 + 3][kk + k2];
#pragma unroll
            for (int j = 0; j < 8; ++j) {
                float w = Ws[k2][tx * 8 + j];
                acc[0][j] = fmaf(a0, w, acc[0][j]);
                acc[1][j] = fmaf(a1, w, acc[1][j]);
                acc[2][j] = fmaf(a2, w, acc[2][j]);
                acc[3][j] = fmaf(a3, w, acc[3][j]);
            }
        }
        __syncthreads();
    }
    // scatter
#pragma unroll
    for (int i = 0; i < 4; ++i) {
        int edge = bm + ty * 4 + i;
        if (edge >= E) continue;
        int d = dst[edge];
#pragma unroll
        for (int j = 0; j < 8; ++j) {
            int col = tx * 8 + j;
            atomicAdd(&agg[(long)d * HD + col], acc[i][j] + b2[col]);
        }
    }
}

// ---------------------------------------------------------------------------
// Fused update: T = relu([h,agg] @ uW1 + ub1);  h += T @ uW2 + ub2
// uW1 is [256,128] with rows 0..127 = h-part, 128..255 = agg-part.
// ---------------------------------------------------------------------------
__global__ __launch_bounds__(256) void upd_k(
    float* __restrict__ h, const float* __restrict__ agg,
    const float* __restrict__ uW1, const float* __restrict__ ub1,
    const float* __restrict__ uW2, const float* __restrict__ ub2, int M)
{
    __shared__ float As[64][33];
    __shared__ float Ws[32][HD];
    __shared__ float P[64][HD + 1];
    const int tid = threadIdx.x, tx = tid & 15, ty = tid >> 4;
    const int bm = blockIdx.x * 64;
    float acc[4][8] = {};

    // Phase A: [h,agg] @ uW1 over K=256
    for (int kk = 0; kk < 2 * HD; kk += 32) {
        int r = tid >> 2, c0 = (tid & 3) * 8, gr = bm + r;
        const float* Asrc = (kk < HD) ? (h + (long)gr * HD + kk) : (agg + (long)gr * HD + (kk - HD));
#pragma unroll
        for (int i = 0; i < 8; ++i)
            As[r][c0 + i] = (gr < M) ? Asrc[c0 + i] : 0.f;
        int k = tid >> 3, n0 = (tid & 7) * 16;
#pragma unroll
        for (int i = 0; i < 16; ++i)
            Ws[k][n0 + i] = uW1[(kk + k) * HD + n0 + i];
        __syncthreads();
#pragma unroll
        for (int k2 = 0; k2 < 32; ++k2) {
            float a0 = As[ty * 4 + 0][k2], a1 = As[ty * 4 + 1][k2];
            float a2 = As[ty * 4 + 2][k2], a3 = As[ty * 4 + 3][k2];
#pragma unroll
            for (int j = 0; j < 8; ++j) {
                float w = Ws[k2][tx * 8 + j];
                acc[0][j] = fmaf(a0, w, acc[0][j]);
                acc[1][j] = fmaf(a1, w, acc[1][j]);
                acc[2][j] = fmaf(a2, w, acc[2][j]);
                acc[3][j] = fmaf(a3, w, acc[3][j]);
            }
        }
        __syncthreads();
    }
#pragma unroll
    for (int i = 0; i < 4; ++i) {
        int row = ty * 4 + i;
#pragma unroll
        for (int j = 0; j < 8; ++j) {
            int col = tx * 8 + j;
            P[row][col] = fmaxf(acc[i][j] + ub1[col], 0.f);
            acc[i][j] = 0.f;
        }
    }
    __syncthreads();
    // Phase B: h += T @ uW2 + ub2
    for (int kk = 0; kk < HD; kk += 32) {
        int k = tid >> 3, n0 = (tid & 7) * 16;
#pragma unroll
        for (int i = 0; i < 16; ++i)
            Ws[k][n0 + i] = uW2[(kk + k) * HD + n0 + i];
        __syncthreads();
#pragma unroll
        for (int k2 = 0; k2 < 32; ++k2) {
            float a0 = P[ty * 4 + 0][kk + k2], a1 = P[ty * 4 + 1][kk + k2];
            float a2 = P[ty * 4 + 2][kk + k2], a3 = P[ty * 4 + 3][kk + k2];
#pragma unroll
            for (int j = 0; j < 8; ++j) {
                float w = Ws[k2][tx * 8 + j];
                acc[0][j] = fmaf(a0, w, acc[0][j]);
                acc[1][j] = fmaf(a1, w, acc[1][j]);
                acc[2][j] = fmaf(a2, w, acc[2][j]);
                acc[3][j] = fmaf(a3, w, acc[3][j]);
            }
        }
        __syncthreads();
    }
#pragma unroll
    for (int i = 0; i < 4; ++i) {
        int gr = bm + ty * 4 + i;
        if (gr >= M) continue;
#pragma unroll
        for (int j = 0; j < 8; ++j) {
            int col = tx * 8 + j;
            h[(long)gr * HD + col] += acc[i][j] + ub2[col];
        }
    }
}

// ---------------------------------------------------------------------------
// Fused decoder: d1 = relu(h@W1+b1); d2 = relu(d1@W2+b2); pred = d2@W3+b3; BC masks
// ---------------------------------------------------------------------------
__global__ __launch_bounds__(256) void dec_k(
    const float* __restrict__ h,
    const float* __restrict__ W1, const float* __restrict__ b1,
    const float* __restrict__ W2, const float* __restrict__ b2,
    const float* __restrict__ W3, const float* __restrict__ b3,
    const float* __restrict__ bc_disp, const float* __restrict__ bc_rot,
    float* __restrict__ outp, int M)
{
    __shared__ float As[64][33];
    __shared__ float Ws[32][HD];
    __shared__ float P[64][HD + 1];
    __shared__ float D2[64][65];
    const int tid = threadIdx.x, tx = tid & 15, ty = tid >> 4;
    const int bm = blockIdx.x * 64;
    float acc[4][8] = {};

    // Phase A: d1 = relu(h @ W1 + b1)
    for (int kk = 0; kk < HD; kk += 32) {
        int r = tid >> 2, c0 = (tid & 3) * 8, gr = bm + r;
#pragma unroll
        for (int i = 0; i < 8; ++i)
            As[r][c0 + i] = (gr < M) ? h[(long)gr * HD + kk + c0 + i] : 0.f;
        int k = tid >> 3, n0 = (tid & 7) * 16;
#pragma unroll
        for (int i = 0; i < 16; ++i)
            Ws[k][n0 + i] = W1[(kk + k) * HD + n0 + i];
        __syncthreads();
#pragma unroll
        for (int k2 = 0; k2 < 32; ++k2) {
            float a0 = As[ty * 4 + 0][k2], a1 = As[ty * 4 + 1][k2];
            float a2 = As[ty * 4 + 2][k2], a3 = As[ty * 4 + 3][k2];
#pragma unroll
            for (int j = 0; j < 8; ++j) {
                float w = Ws[k2][tx * 8 + j];
                acc[0][j] = fmaf(a0, w, acc[0][j]);
                acc[1][j] = fmaf(a1, w, acc[1][j]);
                acc[2][j] = fmaf(a2, w, acc[2][j]);
                acc[3][j] = fmaf(a3, w, acc[3][j]);
            }
        }
        __syncthreads();
    }
#pragma unroll
    for (int i = 0; i < 4; ++i) {
        int row = ty * 4 + i;
#pragma unroll
        for (int j = 0; j < 8; ++j) {
            int col = tx * 8 + j;
            P[row][col] = fmaxf(acc[i][j] + b1[col], 0.f);
        }
    }
    __syncthreads();
    // Phase B: d2 = relu(P @ W2 + b2), 64 cols; each thread owns 4 rows x 4 cols
    float acc2[4][4] = {};
    for (int kk = 0; kk < HD; kk += 32) {
        int idx = tid * 8;  // 32*64 = 2048 elems, 8 per thread
        int k = idx >> 6, n0 = idx & 63;
#pragma unroll
        for (int i = 0; i < 8; ++i)
            Ws[k][n0 + i] = W2[(kk + k) * 64 + n0 + i];
        __syncthreads();
#pragma unroll
        for (int k2 = 0; k2 < 32; ++k2) {
            float a0 = P[ty * 4 + 0][kk + k2], a1 = P[ty * 4 + 1][kk + k2];
            float a2 = P[ty * 4 + 2][kk + k2], a3 = P[ty * 4 + 3][kk + k2];
#pragma unroll
            for (int j = 0; j < 4; ++j) {
                float w = Ws[k2][tx * 4 + j];
                acc2[0][j] = fmaf(a0, w, acc2[0][j]);
                acc2[1][j] = fmaf(a1, w, acc2[1][j]);
                acc2[2][j] = fmaf(a2, w, acc2[2][j]);
                acc2[3][j] = fmaf(a3, w, acc2[3][j]);
            }
        }
        __syncthreads();
    }
#pragma unroll
    for (int i = 0; i < 4; ++i) {
        int row = ty * 4 + i;
#pragma unroll
        for (int j = 0; j < 4; ++j) {
            int col = tx * 4 + j;
            D2[row][col] = fmaxf(acc2[i][j] + b2[col], 0.f);
        }
    }
    __syncthreads();
    // Phase C: pred = d2 @ W3 + b3 (threads 0..63, one row each) + BC masks
    if (tid < 64) {
        int gr = bm + tid;
        if (gr < M) {
            float a0 = b3[0], a1 = b3[1], a2 = b3[2];
#pragma unroll
            for (int k = 0; k < 64; ++k) {
                float v = D2[tid][k];
                a0 = fmaf(v, W3[k * 3 + 0], a0);
                a1 = fmaf(v, W3[k * 3 + 1], a1);
                a2 = fmaf(v, W3[k * 3 + 2], a2);
            }
            outp[gr * 3 + 0] = a0 * (1.f - bc_disp[gr * 2 + 0]);
            outp[gr * 3 + 1] = a1 * (1.f - bc_disp[gr * 2 + 1]);
            outp[gr * 3 + 2] = a2 * (1.f - bc_rot[gr]);
        }
    }
}

// ---------------------------------------------------------------------------
extern "C" void kernel_launch(void* const* d_in, const int* in_sizes, int n_in,
                              void* d_out, int out_size, void* d_ws, size_t ws_size,
                              hipStream_t stream)
{
    const float* x        = (const float*)d_in[0];
    const float* eattr    = (const float*)d_in[1];
    const int*   eidx     = (const int*)d_in[2];
    const float* bc_disp  = (const float*)d_in[3];
    const float* bc_rot   = (const float*)d_in[4];
    const float* enc_n_W1 = (const float*)d_in[5];
    const float* enc_n_b1 = (const float*)d_in[6];
    const float* enc_n_W2 = (const float*)d_in[7];
    const float* enc_n_b2 = (const float*)d_in[8];
    const float* enc_e_W1 = (const float*)d_in[9];
    const float* enc_e_b1 = (const float*)d_in[10];
    const float* enc_e_W2 = (const float*)d_in[11];
    const float* enc_e_b2 = (const float*)d_in[12];
    const float* msg_W1   = (const float*)d_in[13];
    const float* msg_b1   = (const float*)d_in[14];
    const float* msg_W2   = (const float*)d_in[15];
    const float* msg_b2   = (const float*)d_in[16];
    const float* upd_W1   = (const float*)d_in[17];
    const float* upd_b1   = (const float*)d_in[18];
    const float* upd_W2   = (const float*)d_in[19];
    const float* upd_b2   = (const float*)d_in[20];
    const float* dec_W1   = (const float*)d_in[21];
    const float* dec_b1   = (const float*)d_in[22];
    const float* dec_W2   = (const float*)d_in[23];
    const float* dec_b2   = (const float*)d_in[24];
    const float* dec_W3   = (const float*)d_in[25];
    const float* dec_b3   = (const float*)d_in[26];

    const int* src = eidx;
    const int* dst = eidx + NE;

    // workspace: h, Hs, Hd, agg (fp32 NN*HD each) + e (bf16 NE*HD)
    const size_t need = (size_t)4 * NN * HD * sizeof(float) + (size_t)NE * HD * sizeof(bf16);
    if (ws_size < need) {
        // diagnostic fallback: clean absmax failure instead of a memory fault
        long n = out_size;
        zero_out_k<<<(unsigned)((n + 255) / 256), 256, 0, stream>>>((float*)d_out, n);
        return;
    }
    float* h   = (float*)d_ws;
    float* Hs  = h   + (long)NN * HD;
    float* Hd  = Hs  + (long)NN * HD;
    float* agg = Hd  + (long)NN * HD;
    bf16*  e   = (bf16*)(agg + (long)NN * HD);
    float* t1  = Hs;   // aliases for decoder temps (dead by then)

    dim3 blk(256);
    dim3 gN((NN + 63) / 64);
    dim3 gE(NE / 64);

    // encoders
    enc_fused_k<9, float><<<gN, blk, 0, stream>>>(x, enc_n_W1, enc_n_b1, enc_n_W2, enc_n_b2, h, NN);
    enc_fused_k<10, bf16><<<gE, blk, 0, stream>>>(eattr, enc_e_W1, enc_e_b1, enc_e_W2, enc_e_b2, e, NE);

    for (int l = 0; l < 6; ++l) {
        const float* W1a = msg_W1 + (long)l * 384 * HD;
        const float* W1b = W1a + 128 * HD;
        const float* W1c = W1a + 256 * HD;
        const float* b1  = msg_b1 + (long)l * HD;
        const float* W2m = msg_W2 + (long)l * HD * HD;
        const float* b2m = msg_b2 + (long)l * HD;
        const float* uW1 = upd_W1 + (long)l * 256 * HD;
        const float* ub1 = upd_b1 + (long)l * HD;
        const float* uW2 = upd_W2 + (long)l * HD * HD;
        const float* ub2 = upd_b2 + (long)l * HD;

        dualgemm_k<<<gN, blk, 0, stream>>>(h, W1a, W1b, Hs, Hd, NN);
        {
            long n4 = (long)NN * HD / 4;
            zero_k<<<(unsigned)((n4 + 255) / 256), 256, 0, stream>>>((float4*)agg, n4);
        }
        edge_msg_k<<<gE, blk, 0, stream>>>(e, Hs, Hd, src, dst, W1c, b1, W2m, b2m, agg, NE);
        upd_k<<<gN, blk, 0, stream>>>(h, agg, uW1, ub1, uW2, ub2, NN);
    }

    // decoder (Hs/Hd free by now; dec_k is fully fused, no temps needed)
    (void)t1;
    dec_k<<<gN, blk, 0, stream>>>(h, dec_W1, dec_b1, dec_W2, dec_b2, dec_W3, dec_b3,
                                  bc_disp, bc_rot, (float*)d_out, NN);
}

// Round 3
// 2655.926 us; speedup vs baseline: 2.5764x; 2.5764x over previous
//
#include <hip/hip_runtime.h>
#include <hip/hip_bf16.h>

#define NN 50000
#define NE 200000
#define HD 128

typedef unsigned short us4 __attribute__((ext_vector_type(4)));
typedef unsigned short us8 __attribute__((ext_vector_type(8)));

__device__ __forceinline__ float b2f(unsigned short u) {
    union { unsigned i; float f; } v; v.i = ((unsigned)u) << 16; return v.f;
}
__device__ __forceinline__ unsigned short f2b(float x) {
    union { float f; unsigned i; } v; v.f = x;
    unsigned r = v.i + 0x7fffu + ((v.i >> 16) & 1u);
    return (unsigned short)(r >> 16);
}

// ---------------------------------------------------------------------------
// zero / utility kernels
// ---------------------------------------------------------------------------
__global__ __launch_bounds__(256) void zero4_k(float4* __restrict__ p, long n4) {
    long i = (long)blockIdx.x * 256 + threadIdx.x;
    if (i < n4) p[i] = float4{0.f, 0.f, 0.f, 0.f};
}
__global__ __launch_bounds__(256) void zeroi_k(int* __restrict__ p, int n) {
    int i = blockIdx.x * 256 + threadIdx.x;
    if (i < n) p[i] = 0;
}
__global__ __launch_bounds__(256) void zerof_k(float* __restrict__ p, long n) {
    long i = (long)blockIdx.x * 256 + threadIdx.x;
    if (i < n) p[i] = 0.f;
}

// ---------------------------------------------------------------------------
// counting-sort prologue: histogram, 3-phase scan, position build
// ---------------------------------------------------------------------------
__global__ __launch_bounds__(256) void hist_k(const int* __restrict__ dst, int* __restrict__ cnt) {
    int i = blockIdx.x * 256 + threadIdx.x;
    if (i < NE) atomicAdd(&cnt[dst[i]], 1);
}
__global__ __launch_bounds__(256) void scan1_k(const int* __restrict__ cnt, int* __restrict__ bsum) {
    __shared__ int sc[256];
    int i = blockIdx.x * 256 + threadIdx.x;
    sc[threadIdx.x] = (i < NN) ? cnt[i] : 0;
    __syncthreads();
    for (int off = 128; off > 0; off >>= 1) {
        if (threadIdx.x < off) sc[threadIdx.x] += sc[threadIdx.x + off];
        __syncthreads();
    }
    if (threadIdx.x == 0) bsum[blockIdx.x] = sc[0];
}
__global__ __launch_bounds__(256) void scan2_k(int* __restrict__ bsum, int nb) {
    __shared__ int sc[256];
    int t = threadIdx.x;
    int v = (t < nb) ? bsum[t] : 0;
    sc[t] = v;
    __syncthreads();
    for (int off = 1; off < 256; off <<= 1) {
        int a = (t >= off) ? sc[t - off] : 0;
        __syncthreads();
        sc[t] += a;
        __syncthreads();
    }
    if (t < nb) bsum[t] = sc[t] - v;   // exclusive
}
__global__ __launch_bounds__(256) void scan3_k(const int* __restrict__ cnt, const int* __restrict__ bsum,
                                               int* __restrict__ rp, float* __restrict__ deg) {
    __shared__ int sc[256];
    int t = threadIdx.x;
    int i = blockIdx.x * 256 + t;
    int v = (i < NN) ? cnt[i] : 0;
    sc[t] = v;
    __syncthreads();
    for (int off = 1; off < 256; off <<= 1) {
        int a = (t >= off) ? sc[t - off] : 0;
        __syncthreads();
        sc[t] += a;
        __syncthreads();
    }
    int incl = sc[t];
    if (i < NN) {
        rp[i] = bsum[blockIdx.x] + incl - v;
        deg[i] = (float)v;
        if (i == NN - 1) rp[NN] = bsum[blockIdx.x] + incl;
    }
}
__global__ __launch_bounds__(256) void posbuild_k(const int* __restrict__ src, const int* __restrict__ dst,
                                                  const int* __restrict__ rp, int* __restrict__ cur,
                                                  int* __restrict__ pos, int* __restrict__ srcS,
                                                  int* __restrict__ dstS) {
    int i = blockIdx.x * 256 + threadIdx.x;
    if (i >= NE) return;
    int d = dst[i];
    int p = rp[d] + atomicAdd(&cur[d], 1);
    pos[i] = p;
    srcS[p] = src[i];
    dstS[p] = d;
}

// ---------------------------------------------------------------------------
// Shared GEMM tile helpers. 256 threads, 64 rows x 128 cols per block.
// tx = tid&15 owns cols {tx*4..tx*4+3} U {64+tx*4..+3}; ty = tid>>4 owns rows ty*4..+3.
// AsT: transposed A-tile [32 k][65 pad] (odd stride -> conflict-light scalar access).
// Ws: [32 k][128 n] row-major, filled lane-consecutive float4 (conflict-free).
// ---------------------------------------------------------------------------
__device__ __forceinline__ void fillW(float* __restrict__ Ws, const float* __restrict__ Wg, int kk, int tid) {
    float4* s = (float4*)Ws;
    const float4* g = (const float4*)(Wg + (long)kk * HD);
#pragma unroll
    for (int t = 0; t < 4; ++t) s[tid + 256 * t] = g[tid + 256 * t];
}
__device__ __forceinline__ void fillW_g(float* __restrict__ Ws, const float* __restrict__ Wg, int K, int tid) {
    float4* s = (float4*)Ws;
    const float4* g = (const float4*)Wg;
#pragma unroll
    for (int t = 0; t < 4; ++t) {
        int f4 = tid + 256 * t;
        int k = f4 >> 5;
        float4 v = {0.f, 0.f, 0.f, 0.f};
        if (k < K) v = g[f4];
        s[f4] = v;
    }
}
__device__ __forceinline__ void fillA32(float* __restrict__ AsT, const float* __restrict__ A,
                                        int bm, int M, int ldk, int kk, int tid) {
#pragma unroll
    for (int t = 0; t < 2; ++t) {
        int f4 = tid + 256 * t;
        int row = f4 >> 3, c4 = (f4 & 7) * 4;
        int gr = bm + row;
        float4 v = {0.f, 0.f, 0.f, 0.f};
        if (gr < M) v = *(const float4*)(A + (long)gr * ldk + kk + c4);
        AsT[(c4 + 0) * 65 + row] = v.x;
        AsT[(c4 + 1) * 65 + row] = v.y;
        AsT[(c4 + 2) * 65 + row] = v.z;
        AsT[(c4 + 3) * 65 + row] = v.w;
    }
}
__device__ __forceinline__ void fillAb16(float* __restrict__ AsT, const unsigned short* __restrict__ A,
                                         int bm, int M, int kk, int tid) {
    int row = tid >> 2, c8 = (tid & 3) * 8;
    int gr = bm + row;
    us8 v = {0, 0, 0, 0, 0, 0, 0, 0};
    if (gr < M) v = *(const us8*)(A + (long)gr * HD + kk + c8);
#pragma unroll
    for (int i = 0; i < 8; ++i) AsT[(c8 + i) * 65 + row] = b2f(v[i]);
}
// acc[i][j]: j<4 -> col tx*4+j ; j>=4 -> col 64+tx*4+(j-4)
__device__ __forceinline__ void mmac8(float acc[4][8], const float* __restrict__ AsT,
                                      const float* __restrict__ Ws, int tx, int ty) {
#pragma unroll
    for (int k2 = 0; k2 < 32; ++k2) {
        const float* wr = Ws + k2 * HD;
        float4 w0 = *(const float4*)(wr + tx * 4);
        float4 w1 = *(const float4*)(wr + 64 + tx * 4);
        float w[8] = {w0.x, w0.y, w0.z, w0.w, w1.x, w1.y, w1.z, w1.w};
        const float* ar = AsT + k2 * 65 + ty * 4;
        float a0 = ar[0], a1 = ar[1], a2 = ar[2], a3 = ar[3];
#pragma unroll
        for (int j = 0; j < 8; ++j) {
            acc[0][j] = fmaf(a0, w[j], acc[0][j]);
            acc[1][j] = fmaf(a1, w[j], acc[1][j]);
            acc[2][j] = fmaf(a2, w[j], acc[2][j]);
            acc[3][j] = fmaf(a3, w[j], acc[3][j]);
        }
    }
}

// ---------------------------------------------------------------------------
// dual GEMM: Hs = h@W1a, Hd = h@W1b  (bf16 out)
// ---------------------------------------------------------------------------
__global__ __launch_bounds__(256) void dual_k(const float* __restrict__ h,
                                              const float* __restrict__ W1a, const float* __restrict__ W1b,
                                              unsigned short* __restrict__ Hs, unsigned short* __restrict__ Hd,
                                              int M) {
    __shared__ float AsT[32 * 65];
    __shared__ float Wa[32 * HD];
    __shared__ float Wb[32 * HD];
    const int tid = threadIdx.x, tx = tid & 15, ty = tid >> 4;
    const int bm = blockIdx.x * 64;
    float acc1[4][8] = {}, acc2[4][8] = {};
    for (int kk = 0; kk < HD; kk += 32) {
        fillA32(AsT, h, bm, M, HD, kk, tid);
        fillW(Wa, W1a, kk, tid);
        fillW(Wb, W1b, kk, tid);
        __syncthreads();
        mmac8(acc1, AsT, Wa, tx, ty);
        mmac8(acc2, AsT, Wb, tx, ty);
        __syncthreads();
    }
    const int c0 = tx * 4, c1 = 64 + tx * 4;
#pragma unroll
    for (int i = 0; i < 4; ++i) {
        int gr = bm + ty * 4 + i;
        if (gr >= M) continue;
        us4 a0, a1, b0, b1;
#pragma unroll
        for (int j = 0; j < 4; ++j) {
            a0[j] = f2b(acc1[i][j]);     a1[j] = f2b(acc1[i][j + 4]);
            b0[j] = f2b(acc2[i][j]);     b1[j] = f2b(acc2[i][j + 4]);
        }
        *(us4*)(Hs + (long)gr * HD + c0) = a0;  *(us4*)(Hs + (long)gr * HD + c1) = a1;
        *(us4*)(Hd + (long)gr * HD + c0) = b0;  *(us4*)(Hd + (long)gr * HD + c1) = b1;
    }
}

// ---------------------------------------------------------------------------
// edge kernel: P = relu(eS@W1c + b1 + Hs[src] + Hd[dst]); S[dst] += P
// edges are dst-sorted -> run-merged, L2-local atomics.
// ---------------------------------------------------------------------------
__global__ __launch_bounds__(256) void edge_k(const unsigned short* __restrict__ eS,
                                              const unsigned short* __restrict__ Hs,
                                              const unsigned short* __restrict__ Hd,
                                              const int* __restrict__ srcS, const int* __restrict__ dstS,
                                              const float* __restrict__ W1c, const float* __restrict__ b1,
                                              float* __restrict__ S) {
    __shared__ float AsT[32 * 65];
    __shared__ float Ws[32 * HD];
    const int tid = threadIdx.x, tx = tid & 15, ty = tid >> 4;
    const int bm = blockIdx.x * 64;
    float acc[4][8] = {};
    for (int kk = 0; kk < HD; kk += 32) {
        fillAb16(AsT, eS, bm, NE, kk, tid);
        fillW(Ws, W1c, kk, tid);
        __syncthreads();
        mmac8(acc, AsT, Ws, tx, ty);
        __syncthreads();
    }
    const int c0 = tx * 4, c1 = 64 + tx * 4;
    float bv[8];
    *(float4*)&bv[0] = *(const float4*)(b1 + c0);
    *(float4*)&bv[4] = *(const float4*)(b1 + c1);
    float run[8];
    int rd = -1;
#pragma unroll
    for (int i = 0; i < 4; ++i) {
        int edge = bm + ty * 4 + i;
        int s = srcS[edge], d = dstS[edge];
        us4 h0 = *(const us4*)(Hs + (long)s * HD + c0);
        us4 h1 = *(const us4*)(Hs + (long)s * HD + c1);
        us4 g0 = *(const us4*)(Hd + (long)d * HD + c0);
        us4 g1 = *(const us4*)(Hd + (long)d * HD + c1);
        float v[8];
#pragma unroll
        for (int j = 0; j < 4; ++j) {
            v[j]     = fmaxf(acc[i][j]     + bv[j]     + b2f(h0[j]) + b2f(g0[j]), 0.f);
            v[j + 4] = fmaxf(acc[i][j + 4] + bv[j + 4] + b2f(h1[j]) + b2f(g1[j]), 0.f);
        }
        if (d == rd) {
#pragma unroll
            for (int j = 0; j < 8; ++j) run[j] += v[j];
        } else {
            if (rd >= 0) {
#pragma unroll
                for (int j = 0; j < 4; ++j) {
                    atomicAdd(&S[(long)rd * HD + c0 + j], run[j]);
                    atomicAdd(&S[(long)rd * HD + c1 + j], run[j + 4]);
                }
            }
            rd = d;
#pragma unroll
            for (int j = 0; j < 8; ++j) run[j] = v[j];
        }
    }
#pragma unroll
    for (int j = 0; j < 4; ++j) {
        atomicAdd(&S[(long)rd * HD + c0 + j], run[j]);
        atomicAdd(&S[(long)rd * HD + c1 + j], run[j + 4]);
    }
}

// ---------------------------------------------------------------------------
// mini: W2u = W2 @ uW1b  [128,128], b2u = b2 @ uW1b  [128]   (grid = 8 blocks)
// ---------------------------------------------------------------------------
__global__ __launch_bounds__(256) void mini_k(const float* __restrict__ W2m, const float* __restrict__ uW1b,
                                              const float* __restrict__ b2m,
                                              float* __restrict__ W2u, float* __restrict__ b2u) {
    int r = blockIdx.x * 16 + (threadIdx.x >> 4);
    int c0 = (threadIdx.x & 15) * 8;
    float a[8] = {};
    for (int k = 0; k < HD; ++k) {
        float w = W2m[r * HD + k];
        const float* u = uW1b + k * HD + c0;
        float4 u0 = *(const float4*)u, u1 = *(const float4*)(u + 4);
        a[0] = fmaf(w, u0.x, a[0]); a[1] = fmaf(w, u0.y, a[1]);
        a[2] = fmaf(w, u0.z, a[2]); a[3] = fmaf(w, u0.w, a[3]);
        a[4] = fmaf(w, u1.x, a[4]); a[5] = fmaf(w, u1.y, a[5]);
        a[6] = fmaf(w, u1.z, a[6]); a[7] = fmaf(w, u1.w, a[7]);
    }
    *(float4*)(W2u + r * HD + c0)     = float4{a[0], a[1], a[2], a[3]};
    *(float4*)(W2u + r * HD + c0 + 4) = float4{a[4], a[5], a[6], a[7]};
    if (blockIdx.x == 0 && threadIdx.x < 16) {
        int cc = threadIdx.x * 8;
        float b[8] = {};
        for (int k = 0; k < HD; ++k) {
            float w = b2m[k];
            const float* u = uW1b + k * HD + cc;
            float4 u0 = *(const float4*)u, u1 = *(const float4*)(u + 4);
            b[0] = fmaf(w, u0.x, b[0]); b[1] = fmaf(w, u0.y, b[1]);
            b[2] = fmaf(w, u0.z, b[2]); b[3] = fmaf(w, u0.w, b[3]);
            b[4] = fmaf(w, u1.x, b[4]); b[5] = fmaf(w, u1.y, b[5]);
            b[6] = fmaf(w, u1.z, b[6]); b[7] = fmaf(w, u1.w, b[7]);
        }
        *(float4*)(b2u + cc)     = float4{b[0], b[1], b[2], b[3]};
        *(float4*)(b2u + cc + 4) = float4{b[4], b[5], b[6], b[7]};
    }
}

// ---------------------------------------------------------------------------
// update: T = relu(h@uW1a + S@W2u + deg*b2u + ub1);  h += T@uW2 + ub2
// ---------------------------------------------------------------------------
__global__ __launch_bounds__(256) void upd_k(float* __restrict__ h, const float* __restrict__ S,
                                             const float* __restrict__ uW1a, const float* __restrict__ W2u,
                                             const float* __restrict__ ub1, const float* __restrict__ b2u,
                                             const float* __restrict__ deg,
                                             const float* __restrict__ uW2, const float* __restrict__ ub2,
                                             int M) {
    __shared__ float AsT[32 * 65];
    __shared__ float Ws[32 * HD];
    __shared__ float PT[128 * 65];
    const int tid = threadIdx.x, tx = tid & 15, ty = tid >> 4;
    const int bm = blockIdx.x * 64;
    float acc[4][8] = {};
    for (int kk = 0; kk < HD; kk += 32) {
        fillA32(AsT, h, bm, M, HD, kk, tid);
        fillW(Ws, uW1a, kk, tid);
        __syncthreads();
        mmac8(acc, AsT, Ws, tx, ty);
        __syncthreads();
    }
    for (int kk = 0; kk < HD; kk += 32) {
        fillA32(AsT, S, bm, M, HD, kk, tid);
        fillW(Ws, W2u, kk, tid);
        __syncthreads();
        mmac8(acc, AsT, Ws, tx, ty);
        __syncthreads();
    }
    const int c0 = tx * 4, c1 = 64 + tx * 4;
    float b1v[8], b2v[8];
    *(float4*)&b1v[0] = *(const float4*)(ub1 + c0);
    *(float4*)&b1v[4] = *(const float4*)(ub1 + c1);
    *(float4*)&b2v[0] = *(const float4*)(b2u + c0);
    *(float4*)&b2v[4] = *(const float4*)(b2u + c1);
#pragma unroll
    for (int i = 0; i < 4; ++i) {
        int gr = bm + ty * 4 + i;
        float dg = (gr < M) ? deg[gr] : 0.f;
        int row = ty * 4 + i;
#pragma unroll
        for (int j = 0; j < 4; ++j) {
            PT[(c0 + j) * 65 + row] = fmaxf(acc[i][j]     + b1v[j]     + dg * b2v[j],     0.f);
            PT[(c1 + j) * 65 + row] = fmaxf(acc[i][j + 4] + b1v[j + 4] + dg * b2v[j + 4], 0.f);
            acc[i][j] = 0.f; acc[i][j + 4] = 0.f;
        }
    }
    __syncthreads();
    for (int kk = 0; kk < HD; kk += 32) {
        fillW(Ws, uW2, kk, tid);
        __syncthreads();
        mmac8(acc, PT + kk * 65, Ws, tx, ty);
        __syncthreads();
    }
    float b3v[8];
    *(float4*)&b3v[0] = *(const float4*)(ub2 + c0);
    *(float4*)&b3v[4] = *(const float4*)(ub2 + c1);
#pragma unroll
    for (int i = 0; i < 4; ++i) {
        int gr = bm + ty * 4 + i;
        if (gr >= M) continue;
        float4* hp0 = (float4*)(h + (long)gr * HD + c0);
        float4* hp1 = (float4*)(h + (long)gr * HD + c1);
        float4 v0 = hp0[0], v1 = hp1[0];
        v0.x += acc[i][0] + b3v[0]; v0.y += acc[i][1] + b3v[1];
        v0.z += acc[i][2] + b3v[2]; v0.w += acc[i][3] + b3v[3];
        v1.x += acc[i][4] + b3v[4]; v1.y += acc[i][5] + b3v[5];
        v1.z += acc[i][6] + b3v[6]; v1.w += acc[i][7] + b3v[7];
        hp0[0] = v0; hp1[0] = v1;
    }
}

// ---------------------------------------------------------------------------
// fused 2-layer encoder; SCAT=true scatters bf16 rows via pos (edge encoder)
// ---------------------------------------------------------------------------
template<int KIN, bool SCAT>
__global__ __launch_bounds__(256) void enc_k(const float* __restrict__ A,
                                             const float* __restrict__ W1, const float* __restrict__ b1,
                                             const float* __restrict__ W2, const float* __restrict__ b2,
                                             float* __restrict__ outF, unsigned short* __restrict__ outB,
                                             const int* __restrict__ pos, int M) {
    __shared__ float AsT[32 * 65];
    __shared__ float Ws[32 * HD];
    __shared__ float PT[128 * 65];
    const int tid = threadIdx.x, tx = tid & 15, ty = tid >> 4;
    const int bm = blockIdx.x * 64;
    float acc[4][8] = {};
    {   // phase A: single padded K-chunk (KIN <= 32)
        int row = tid >> 2, q = tid & 3, gr = bm + row;
#pragma unroll
        for (int i = 0; i < 8; ++i) {
            int k = q * 8 + i;
            float v = 0.f;
            if (gr < M && k < KIN) v = A[(long)gr * KIN + k];
            AsT[k * 65 + row] = v;
        }
        fillW_g(Ws, W1, KIN, tid);
        __syncthreads();
        mmac8(acc, AsT, Ws, tx, ty);
        __syncthreads();
    }
    const int c0 = tx * 4, c1 = 64 + tx * 4;
    float bv[8];
    *(float4*)&bv[0] = *(const float4*)(b1 + c0);
    *(float4*)&bv[4] = *(const float4*)(b1 + c1);
#pragma unroll
    for (int i = 0; i < 4; ++i) {
        int row = ty * 4 + i;
#pragma unroll
        for (int j = 0; j < 4; ++j) {
            PT[(c0 + j) * 65 + row] = fmaxf(acc[i][j]     + bv[j],     0.f);
            PT[(c1 + j) * 65 + row] = fmaxf(acc[i][j + 4] + bv[j + 4], 0.f);
            acc[i][j] = 0.f; acc[i][j + 4] = 0.f;
        }
    }
    __syncthreads();
    for (int kk = 0; kk < HD; kk += 32) {
        fillW(Ws, W2, kk, tid);
        __syncthreads();
        mmac8(acc, PT + kk * 65, Ws, tx, ty);
        __syncthreads();
    }
    float b2v[8];
    *(float4*)&b2v[0] = *(const float4*)(b2 + c0);
    *(float4*)&b2v[4] = *(const float4*)(b2 + c1);
#pragma unroll
    for (int i = 0; i < 4; ++i) {
        int gr = bm + ty * 4 + i;
        if (gr >= M) continue;
        if constexpr (SCAT) {
            int p = pos[gr];
            us4 o0, o1;
#pragma unroll
            for (int j = 0; j < 4; ++j) {
                o0[j] = f2b(acc[i][j] + b2v[j]);
                o1[j] = f2b(acc[i][j + 4] + b2v[j + 4]);
            }
            *(us4*)(outB + (long)p * HD + c0) = o0;
            *(us4*)(outB + (long)p * HD + c1) = o1;
        } else {
            float4 o0{acc[i][0] + b2v[0], acc[i][1] + b2v[1], acc[i][2] + b2v[2], acc[i][3] + b2v[3]};
            float4 o1{acc[i][4] + b2v[4], acc[i][5] + b2v[5], acc[i][6] + b2v[6], acc[i][7] + b2v[7]};
            *(float4*)(outF + (long)gr * HD + c0) = o0;
            *(float4*)(outF + (long)gr * HD + c1) = o1;
        }
    }
}

// ---------------------------------------------------------------------------
// fused decoder (kept from round 2 — known-correct, 1 dispatch)
// ---------------------------------------------------------------------------
__global__ __launch_bounds__(256) void dec_k(
    const float* __restrict__ h,
    const float* __restrict__ W1, const float* __restrict__ b1,
    const float* __restrict__ W2, const float* __restrict__ b2,
    const float* __restrict__ W3, const float* __restrict__ b3,
    const float* __restrict__ bc_disp, const float* __restrict__ bc_rot,
    float* __restrict__ outp, int M)
{
    __shared__ float As[64][33];
    __shared__ float Ws[32][HD];
    __shared__ float P[64][HD + 1];
    __shared__ float D2[64][65];
    const int tid = threadIdx.x, tx = tid & 15, ty = tid >> 4;
    const int bm = blockIdx.x * 64;
    float acc[4][8] = {};

    for (int kk = 0; kk < HD; kk += 32) {
        int r = tid >> 2, cc0 = (tid & 3) * 8, gr = bm + r;
#pragma unroll
        for (int i = 0; i < 8; ++i)
            As[r][cc0 + i] = (gr < M) ? h[(long)gr * HD + kk + cc0 + i] : 0.f;
        int k = tid >> 3, n0 = (tid & 7) * 16;
#pragma unroll
        for (int i = 0; i < 16; ++i)
            Ws[k][n0 + i] = W1[(kk + k) * HD + n0 + i];
        __syncthreads();
#pragma unroll
        for (int k2 = 0; k2 < 32; ++k2) {
            float a0 = As[ty * 4 + 0][k2], a1 = As[ty * 4 + 1][k2];
            float a2 = As[ty * 4 + 2][k2], a3 = As[ty * 4 + 3][k2];
#pragma unroll
            for (int j = 0; j < 8; ++j) {
                float w = Ws[k2][tx * 8 + j];
                acc[0][j] = fmaf(a0, w, acc[0][j]);
                acc[1][j] = fmaf(a1, w, acc[1][j]);
                acc[2][j] = fmaf(a2, w, acc[2][j]);
                acc[3][j] = fmaf(a3, w, acc[3][j]);
            }
        }
        __syncthreads();
    }
#pragma unroll
    for (int i = 0; i < 4; ++i) {
        int row = ty * 4 + i;
#pragma unroll
        for (int j = 0; j < 8; ++j) {
            int col = tx * 8 + j;
            P[row][col] = fmaxf(acc[i][j] + b1[col], 0.f);
        }
    }
    __syncthreads();
    float acc2[4][4] = {};
    for (int kk = 0; kk < HD; kk += 32) {
        int idx = tid * 8;
        int k = idx >> 6, n0 = idx & 63;
#pragma unroll
        for (int i = 0; i < 8; ++i)
            Ws[k][n0 + i] = W2[(kk + k) * 64 + n0 + i];
        __syncthreads();
#pragma unroll
        for (int k2 = 0; k2 < 32; ++k2) {
            float a0 = P[ty * 4 + 0][kk + k2], a1 = P[ty * 4 + 1][kk + k2];
            float a2 = P[ty * 4 + 2][kk + k2], a3 = P[ty * 4 + 3][kk + k2];
#pragma unroll
            for (int j = 0; j < 4; ++j) {
                float w = Ws[k2][tx * 4 + j];
                acc2[0][j] = fmaf(a0, w, acc2[0][j]);
                acc2[1][j] = fmaf(a1, w, acc2[1][j]);
                acc2[2][j] = fmaf(a2, w, acc2[2][j]);
                acc2[3][j] = fmaf(a3, w, acc2[3][j]);
            }
        }
        __syncthreads();
    }
#pragma unroll
    for (int i = 0; i < 4; ++i) {
        int row = ty * 4 + i;
#pragma unroll
        for (int j = 0; j < 4; ++j) {
            int col = tx * 4 + j;
            D2[row][col] = fmaxf(acc2[i][j] + b2[col], 0.f);
        }
    }
    __syncthreads();
    if (tid < 64) {
        int gr = bm + tid;
        if (gr < M) {
            float a0 = b3[0], a1 = b3[1], a2 = b3[2];
#pragma unroll
            for (int k = 0; k < 64; ++k) {
                float v = D2[tid][k];
                a0 = fmaf(v, W3[k * 3 + 0], a0);
                a1 = fmaf(v, W3[k * 3 + 1], a1);
                a2 = fmaf(v, W3[k * 3 + 2], a2);
            }
            outp[gr * 3 + 0] = a0 * (1.f - bc_disp[gr * 2 + 0]);
            outp[gr * 3 + 1] = a1 * (1.f - bc_disp[gr * 2 + 1]);
            outp[gr * 3 + 2] = a2 * (1.f - bc_rot[gr]);
        }
    }
}

// ---------------------------------------------------------------------------
extern "C" void kernel_launch(void* const* d_in, const int* in_sizes, int n_in,
                              void* d_out, int out_size, void* d_ws, size_t ws_size,
                              hipStream_t stream)
{
    const float* x        = (const float*)d_in[0];
    const float* eattr    = (const float*)d_in[1];
    const int*   eidx     = (const int*)d_in[2];
    const float* bc_disp  = (const float*)d_in[3];
    const float* bc_rot   = (const float*)d_in[4];
    const float* enc_n_W1 = (const float*)d_in[5];
    const float* enc_n_b1 = (const float*)d_in[6];
    const float* enc_n_W2 = (const float*)d_in[7];
    const float* enc_n_b2 = (const float*)d_in[8];
    const float* enc_e_W1 = (const float*)d_in[9];
    const float* enc_e_b1 = (const float*)d_in[10];
    const float* enc_e_W2 = (const float*)d_in[11];
    const float* enc_e_b2 = (const float*)d_in[12];
    const float* msg_W1   = (const float*)d_in[13];
    const float* msg_b1   = (const float*)d_in[14];
    const float* msg_W2   = (const float*)d_in[15];
    const float* msg_b2   = (const float*)d_in[16];
    const float* upd_W1   = (const float*)d_in[17];
    const float* upd_b1   = (const float*)d_in[18];
    const float* upd_W2   = (const float*)d_in[19];
    const float* upd_b2   = (const float*)d_in[20];
    const float* dec_W1   = (const float*)d_in[21];
    const float* dec_b1   = (const float*)d_in[22];
    const float* dec_W2   = (const float*)d_in[23];
    const float* dec_b2   = (const float*)d_in[24];
    const float* dec_W3   = (const float*)d_in[25];
    const float* dec_b3   = (const float*)d_in[26];

    const int* src = eidx;
    const int* dst = eidx + NE;

    // workspace layout
    char* base = (char*)d_ws;
    float* h  = (float*)base;                              // NN*HD f32
    float* S  = h + (long)NN * HD;                         // NN*HD f32
    unsigned short* Hs = (unsigned short*)(S + (long)NN * HD);  // NN*HD bf16
    unsigned short* Hd = Hs + (long)NN * HD;               // NN*HD bf16
    unsigned short* eS = Hd + (long)NN * HD;               // NE*HD bf16
    float* W2u = (float*)(eS + (long)NE * HD);             // 128*128 f32
    float* b2u = W2u + HD * HD;                            // 128 f32
    float* deg = b2u + HD;                                 // NN f32
    int* rowp  = (int*)(deg + NN);                         // NN+1
    int* cnt   = rowp + (NN + 1);                          // NN (also cursor)
    int* posb  = cnt + NN;                                 // NE
    int* srcS  = posb + NE;                                // NE
    int* dstS  = srcS + NE;                                // NE
    int* bsum  = dstS + NE;                                // 256
    size_t need = (size_t)((char*)(bsum + 256) - base);
    if (ws_size < need) {
        zerof_k<<<(unsigned)((out_size + 255) / 256), 256, 0, stream>>>((float*)d_out, out_size);
        return;
    }

    dim3 blk(256);
    const unsigned gN  = (NN + 63) / 64;    // 782
    const unsigned gE  = NE / 64;           // 3125
    const unsigned gNc = (NN + 255) / 256;  // 196
    const unsigned gEc = (NE + 255) / 256;  // 782

    // --- prologue: counting sort of edges by dst ---
    zeroi_k<<<gNc, blk, 0, stream>>>(cnt, NN);
    hist_k<<<gEc, blk, 0, stream>>>(dst, cnt);
    scan1_k<<<gNc, blk, 0, stream>>>(cnt, bsum);
    scan2_k<<<1, blk, 0, stream>>>(bsum, (int)gNc);
    scan3_k<<<gNc, blk, 0, stream>>>(cnt, bsum, rowp, deg);
    zeroi_k<<<gNc, blk, 0, stream>>>(cnt, NN);   // reuse as cursor
    posbuild_k<<<gEc, blk, 0, stream>>>(src, dst, rowp, cnt, posb, srcS, dstS);

    // --- encoders ---
    enc_k<9, false><<<gN, blk, 0, stream>>>(x, enc_n_W1, enc_n_b1, enc_n_W2, enc_n_b2,
                                            h, nullptr, nullptr, NN);
    enc_k<10, true><<<gE, blk, 0, stream>>>(eattr, enc_e_W1, enc_e_b1, enc_e_W2, enc_e_b2,
                                            nullptr, eS, posb, NE);

    // --- message-passing layers ---
    for (int l = 0; l < 6; ++l) {
        const float* W1a = msg_W1 + (long)l * 384 * HD;
        const float* W1b = W1a + 128 * HD;
        const float* W1c = W1a + 256 * HD;
        const float* b1  = msg_b1 + (long)l * HD;
        const float* W2m = msg_W2 + (long)l * HD * HD;
        const float* b2m = msg_b2 + (long)l * HD;
        const float* uW1a = upd_W1 + (long)l * 256 * HD;
        const float* uW1b = uW1a + 128 * HD;
        const float* ub1  = upd_b1 + (long)l * HD;
        const float* uW2  = upd_W2 + (long)l * HD * HD;
        const float* ub2  = upd_b2 + (long)l * HD;

        dual_k<<<gN, blk, 0, stream>>>(h, W1a, W1b, Hs, Hd, NN);
        {
            long n4 = (long)NN * HD / 4;
            zero4_k<<<(unsigned)((n4 + 255) / 256), blk, 0, stream>>>((float4*)S, n4);
        }
        edge_k<<<gE, blk, 0, stream>>>(eS, Hs, Hd, srcS, dstS, W1c, b1, S);
        mini_k<<<8, blk, 0, stream>>>(W2m, uW1b, b2m, W2u, b2u);
        upd_k<<<gN, blk, 0, stream>>>(h, S, uW1a, W2u, ub1, b2u, deg, uW2, ub2, NN);
    }

    // --- decoder ---
    dec_k<<<gN, blk, 0, stream>>>(h, dec_W1, dec_b1, dec_W2, dec_b2, dec_W3, dec_b3,
                                  bc_disp, bc_rot, (float*)d_out, NN);
}